// Round 1
// baseline (40722.861 us; speedup 1.0000x reference)
//
#include <hip/hip_runtime.h>

typedef _Float16 f16;
typedef __attribute__((ext_vector_type(4))) _Float16 f16x4;
typedef __attribute__((ext_vector_type(8))) _Float16 f16x8;
typedef __attribute__((ext_vector_type(4))) float f32x4;

#define NB 8
#define NS 4096
#define NIN 512
#define NDIN 1024
#define NH 512
#define NG4 2048
#define NPROJ 960

// workspace layout (bytes)
static const size_t OFF_XH  = 0;                                  // f16 [NB*NS][NDIN]   = 64 MB
static const size_t OFF_GX  = (size_t)NB*NS*NDIN*2;               // f16 [NB*NS][NG4]    = 128 MB
static const size_t OFF_H0  = OFF_GX + (size_t)NB*NS*NG4*2;       // f16 [2][16][512]
static const size_t OFF_H1  = OFF_H0 + 32768;                     // f16 [2][16][512]
static const size_t OFF_CNT = OFF_H1 + 32768;                     // unsigned + pad (256B)

__device__ __forceinline__ float sigf(float x)  { return 1.f/(1.f+__expf(-x)); }
__device__ __forceinline__ float tanh_(float x) { return 2.f/(1.f+__expf(-2.f*x)) - 1.f; }

__device__ __forceinline__ f16x8 cvt8(const float* p) {
  float4 a = *(const float4*)p;
  float4 b = *(const float4*)(p+4);
  f16x8 r = {(f16)a.x,(f16)a.y,(f16)a.z,(f16)a.w,(f16)b.x,(f16)b.y,(f16)b.z,(f16)b.w};
  return r;
}

__global__ void init_kernel(unsigned* __restrict__ p, int n) {
  int i = blockIdx.x*blockDim.x + threadIdx.x;
  for (; i < n; i += gridDim.x*blockDim.x) p[i] = 0u;
}

// xh[bt][960+j] = emb[idx[bt]][j]
__global__ void emb_kernel(const int* __restrict__ idx, const float* __restrict__ emb,
                           f16* __restrict__ xh) {
  int g  = blockIdx.x*blockDim.x + threadIdx.x;   // 32768*16 threads
  int bt = g >> 4;
  int j  = (g & 15) << 2;
  int id = idx[bt];
  float4 v = *(const float4*)(emb + id*64 + j);
  f16x4 h = {(f16)v.x,(f16)v.y,(f16)v.z,(f16)v.w};
  *(f16x4*)(xh + (size_t)bt*NDIN + NPROJ + j) = h;
}

// xh[:, 0:960] = relu(WS @ Wp^T + bp), f16 out.  M=32768, N=960(pad 1024), K=512
__global__ __launch_bounds__(256) void proj_kernel(
    const float* __restrict__ wst, const float* __restrict__ Wp,
    const float* __restrict__ bp, f16* __restrict__ xh) {
  __shared__ f16 Asl[128*40];
  __shared__ f16 Bsl[128*40];
  const int tid = threadIdx.x;
  const int lane = tid & 63;
  const int wv = tid >> 6;
  const int wm = wv >> 1, wn = wv & 1;
  const int lm = lane & 15;
  const int kq = lane >> 4;
  const int kg8 = kq << 3;
  const int m0 = blockIdx.x * 128;
  const int n0 = blockIdx.y * 128;
  f32x4 acc[4][4];
#pragma unroll
  for (int a = 0; a < 4; ++a)
#pragma unroll
    for (int b = 0; b < 4; ++b) acc[a][b] = (f32x4){0.f,0.f,0.f,0.f};
  for (int k0 = 0; k0 < NIN; k0 += 32) {
#pragma unroll
    for (int i = 0; i < 4; ++i) {
      int c = tid + (i << 8);
      int row = c >> 3;
      int kc = (c & 7) << 2;
      {
        float4 v = *(const float4*)(wst + (size_t)(m0+row)*NIN + k0 + kc);
        f16x4 h = {(f16)v.x,(f16)v.y,(f16)v.z,(f16)v.w};
        *(f16x4*)&Asl[row*40 + kc] = h;
      }
      {
        int nr = n0 + row; nr = nr < NPROJ ? nr : (NPROJ-1);
        float4 v = *(const float4*)(Wp + (size_t)nr*NIN + k0 + kc);
        f16x4 h = {(f16)v.x,(f16)v.y,(f16)v.z,(f16)v.w};
        *(f16x4*)&Bsl[row*40 + kc] = h;
      }
    }
    __syncthreads();
    f16x8 af[4], bf[4];
#pragma unroll
    for (int f = 0; f < 4; ++f) af[f] = *(f16x8*)&Asl[(wm*64 + f*16 + lm)*40 + kg8];
#pragma unroll
    for (int f = 0; f < 4; ++f) bf[f] = *(f16x8*)&Bsl[(wn*64 + f*16 + lm)*40 + kg8];
#pragma unroll
    for (int a = 0; a < 4; ++a)
#pragma unroll
      for (int b = 0; b < 4; ++b)
        acc[a][b] = __builtin_amdgcn_mfma_f32_16x16x32_f16(af[a], bf[b], acc[a][b], 0,0,0);
    __syncthreads();
  }
#pragma unroll
  for (int a = 0; a < 4; ++a)
#pragma unroll
    for (int b = 0; b < 4; ++b) {
      int n = n0 + wn*64 + b*16 + lm;
      if (n < NPROJ) {
        float bias = bp[n];
#pragma unroll
        for (int j = 0; j < 4; ++j) {
          int m = m0 + wm*64 + a*16 + (kq<<2) + j;
          float v = acc[a][b][j] + bias;
          xh[(size_t)m*NDIN + n] = (f16)fmaxf(v, 0.f);
        }
      }
    }
}

// gx = xh @ Wih0p^T + b0p (gate-permuted cols: prow=4u+g <- orig g*512+u). f16 out.
// M=32768, N=2048, K=1024
__global__ __launch_bounds__(256) void gx_kernel(
    const f16* __restrict__ xh, const float* __restrict__ Wih0,
    const float* __restrict__ bih0, const float* __restrict__ bhh0,
    f16* __restrict__ gx) {
  __shared__ f16 Asl[128*40];
  __shared__ f16 Bsl[128*40];
  const int tid = threadIdx.x;
  const int lane = tid & 63;
  const int wv = tid >> 6;
  const int wm = wv >> 1, wn = wv & 1;
  const int lm = lane & 15;
  const int kq = lane >> 4;
  const int kg8 = kq << 3;
  const int m0 = blockIdx.x * 128;
  const int n0 = blockIdx.y * 128;
  f32x4 acc[4][4];
#pragma unroll
  for (int a = 0; a < 4; ++a)
#pragma unroll
    for (int b = 0; b < 4; ++b) acc[a][b] = (f32x4){0.f,0.f,0.f,0.f};
  for (int k0 = 0; k0 < NDIN; k0 += 32) {
#pragma unroll
    for (int i = 0; i < 2; ++i) {                 // A: 512 chunks of 8 halves
      int c = tid + (i << 8);
      int row = c >> 2;
      int kc = (c & 3) << 3;
      f16x8 v = *(const f16x8*)(xh + (size_t)(m0+row)*NDIN + k0 + kc);
      *(f16x8*)&Asl[row*40 + kc] = v;
    }
#pragma unroll
    for (int i = 0; i < 4; ++i) {                 // B: permuted Wih0 rows, fp32->f16
      int c = tid + (i << 8);
      int row = c >> 3;
      int kc = (c & 7) << 2;
      int n = n0 + row;
      int orig = ((n & 3) << 9) | (n >> 2);
      float4 v = *(const float4*)(Wih0 + (size_t)orig*NDIN + k0 + kc);
      f16x4 h = {(f16)v.x,(f16)v.y,(f16)v.z,(f16)v.w};
      *(f16x4*)&Bsl[row*40 + kc] = h;
    }
    __syncthreads();
    f16x8 af[4], bf[4];
#pragma unroll
    for (int f = 0; f < 4; ++f) af[f] = *(f16x8*)&Asl[(wm*64 + f*16 + lm)*40 + kg8];
#pragma unroll
    for (int f = 0; f < 4; ++f) bf[f] = *(f16x8*)&Bsl[(wn*64 + f*16 + lm)*40 + kg8];
#pragma unroll
    for (int a = 0; a < 4; ++a)
#pragma unroll
      for (int b = 0; b < 4; ++b)
        acc[a][b] = __builtin_amdgcn_mfma_f32_16x16x32_f16(af[a], bf[b], acc[a][b], 0,0,0);
    __syncthreads();
  }
#pragma unroll
  for (int a = 0; a < 4; ++a)
#pragma unroll
    for (int b = 0; b < 4; ++b) {
      int n = n0 + wn*64 + b*16 + lm;
      int orig = ((n & 3) << 9) | (n >> 2);
      float bias = bih0[orig] + bhh0[orig];
#pragma unroll
      for (int j = 0; j < 4; ++j) {
        int m = m0 + wm*64 + a*16 + (kq<<2) + j;
        gx[(size_t)m*NG4 + n] = (f16)(acc[a][b][j] + bias);
      }
    }
}

// Persistent sequential LSTM. 32 WGs x 512 thr = 256 waves.
// waves 0..127: layer-0 gate tile rt=w (16 permuted rows of Whh0), step p
// waves 128..255: layer-1 gate tile (Wih1|Whh1), step p-1
// One device barrier per phase; weights live in VGPRs; c-state in lane registers.
__global__ __launch_bounds__(512, 2) void seq_kernel(
    const f16* __restrict__ gx, const float* __restrict__ Whh0,
    const float* __restrict__ Wih1, const float* __restrict__ Whh1,
    const float* __restrict__ bih1, const float* __restrict__ bhh1,
    f16* __restrict__ h0b, f16* __restrict__ h1b,
    unsigned* __restrict__ cnt, float* __restrict__ out) {
  const int tid  = threadIdx.x;
  const int lane = tid & 63;
  const int w    = (blockIdx.x << 3) + (tid >> 6);
  const bool isG0 = (w < 128);
  const int rt = isG0 ? w : (w - 128);
  const int lm  = lane & 15;         // A-row-in-tile / D-col(batch)
  const int kq  = lane >> 4;         // k-quarter / D-row-group
  const int kg8 = kq << 3;
  const int prow = (rt << 4) + lm;                 // permuted gate row this lane loads
  const int orig = ((prow & 3) << 9) | (prow >> 2);
  const int u    = (rt << 2) + kq;                 // hidden unit this lane owns (elementwise)
  const int bb   = (lm < 8) ? lm : 0;
  const bool act = (lm < 8);

  f16x8 wA[16], wB[16];
  if (isG0) {
    const float* s = Whh0 + (size_t)orig * NH;
#pragma unroll
    for (int kt = 0; kt < 16; ++kt) wA[kt] = cvt8(s + kt*32 + kg8);
#pragma unroll
    for (int kt = 0; kt < 16; ++kt) wB[kt] = wA[kt];   // unused by G0 path
  } else {
    const float* s1 = Wih1 + (size_t)orig * NH;
    const float* s2 = Whh1 + (size_t)orig * NH;
#pragma unroll
    for (int kt = 0; kt < 16; ++kt) wA[kt] = cvt8(s1 + kt*32 + kg8);
#pragma unroll
    for (int kt = 0; kt < 16; ++kt) wB[kt] = cvt8(s2 + kt*32 + kg8);
  }
  float bias1_[4] = {0.f,0.f,0.f,0.f};
  if (!isG0) {
#pragma unroll
    for (int j = 0; j < 4; ++j) bias1_[j] = bih1[j*NH + u] + bhh1[j*NH + u];
  }

  float cst = 0.f, hlast = 0.f;
  const unsigned nwg = gridDim.x;

  for (int p = 0; p <= NS; ++p) {
    const int qr = (p + 1) & 1;    // buffer holding h(prev)
    const int qw = p & 1;          // buffer to write h0(p)
    if (isG0) {
      if (p < NS) {
        f16x4 g4 = *(const f16x4*)(gx + ((size_t)bb*NS + p)*NG4 + (u << 2));
        const f16* hp = h0b + qr*8192 + (lm << 9);
        f32x4 acc = (f32x4){0.f,0.f,0.f,0.f};
#pragma unroll
        for (int kt = 0; kt < 16; ++kt) {
          f16x8 bfr = *(const f16x8*)(hp + kt*32 + kg8);
          acc = __builtin_amdgcn_mfma_f32_16x16x32_f16(wA[kt], bfr, acc, 0,0,0);
        }
        float gi = acc[0] + (float)g4[0];
        float gf = acc[1] + (float)g4[1];
        float gg = acc[2] + (float)g4[2];
        float go = acc[3] + (float)g4[3];
        cst = sigf(gf)*cst + sigf(gi)*tanh_(gg);
        float h = sigf(go)*tanh_(cst);
        hlast = h;
        if (act) h0b[qw*8192 + (lm << 9) + u] = (f16)h;
      }
    } else {
      if (p >= 1) {
        const f16* hp0 = h0b + qr*8192 + (lm << 9);   // h0(p-1)
        const f16* hp1 = h1b + qw*8192 + (lm << 9);   // h1(p-2)
        f32x4 acc = (f32x4){0.f,0.f,0.f,0.f};
#pragma unroll
        for (int kt = 0; kt < 16; ++kt) {
          f16x8 bfr = *(const f16x8*)(hp0 + kt*32 + kg8);
          acc = __builtin_amdgcn_mfma_f32_16x16x32_f16(wA[kt], bfr, acc, 0,0,0);
        }
#pragma unroll
        for (int kt = 0; kt < 16; ++kt) {
          f16x8 bfr = *(const f16x8*)(hp1 + kt*32 + kg8);
          acc = __builtin_amdgcn_mfma_f32_16x16x32_f16(wB[kt], bfr, acc, 0,0,0);
        }
        float gi = acc[0] + bias1_[0];
        float gf = acc[1] + bias1_[1];
        float gg = acc[2] + bias1_[2];
        float go = acc[3] + bias1_[3];
        cst = sigf(gf)*cst + sigf(gi)*tanh_(gg);
        float h = sigf(go)*tanh_(cst);
        hlast = h;
        if (act) {
          h1b[qr*8192 + (lm << 9) + u] = (f16)h;              // buf (p-1)&1
          out[((size_t)lm*NS + (p-1))*NH + u] = h;            // rnn_out fp32
        }
      }
    }
    // device barrier across all WGs
    __syncthreads();
    if (tid == 0) {
      __hip_atomic_fetch_add(cnt, 1u, __ATOMIC_RELEASE, __HIP_MEMORY_SCOPE_AGENT);
      const unsigned tgt = nwg * (unsigned)(p + 1);
      while (__hip_atomic_load(cnt, __ATOMIC_ACQUIRE, __HIP_MEMORY_SCOPE_AGENT) < tgt) {
        __builtin_amdgcn_s_sleep(1);
      }
    }
    __syncthreads();
  }

  // final hidden/cell states
  if (act) {
    const size_t HID = (size_t)NB*NS*NH;     // 16777216
    size_t base = (size_t)lm*NH + u;
    if (isG0) {
      out[HID + base] = hlast;               // hidden[0]
      out[HID + 8192 + base] = cst;          // cell[0]
    } else {
      out[HID + 4096 + base] = hlast;        // hidden[1]
      out[HID + 8192 + 4096 + base] = cst;   // cell[1]
    }
  }
}

extern "C" void kernel_launch(void* const* d_in, const int* in_sizes, int n_in,
                              void* d_out, int out_size, void* d_ws, size_t ws_size,
                              hipStream_t stream) {
  const float* wst  = (const float*)d_in[0];
  const int*   idx  = (const int*)  d_in[1];
  const float* emb  = (const float*)d_in[2];
  const float* Wp   = (const float*)d_in[3];
  const float* bp   = (const float*)d_in[4];
  const float* Wih0 = (const float*)d_in[5];
  const float* Whh0 = (const float*)d_in[6];
  const float* bih0 = (const float*)d_in[7];
  const float* bhh0 = (const float*)d_in[8];
  const float* Wih1 = (const float*)d_in[9];
  const float* Whh1 = (const float*)d_in[10];
  const float* bih1 = (const float*)d_in[11];
  const float* bhh1 = (const float*)d_in[12];
  float* out = (float*)d_out;
  char* wsb = (char*)d_ws;
  f16* xh  = (f16*)(wsb + OFF_XH);
  f16* gx  = (f16*)(wsb + OFF_GX);
  f16* h0b = (f16*)(wsb + OFF_H0);
  f16* h1b = (f16*)(wsb + OFF_H1);
  unsigned* cnt = (unsigned*)(wsb + OFF_CNT);

  // zero h buffers + barrier counter (ws is poisoned before every launch)
  hipLaunchKernelGGL(init_kernel, dim3(32), dim3(256), 0, stream,
                     (unsigned*)(wsb + OFF_H0), (int)((32768 + 32768 + 256) / 4));
  hipLaunchKernelGGL(proj_kernel, dim3(256, 8), dim3(256), 0, stream, wst, Wp, bp, xh);
  hipLaunchKernelGGL(emb_kernel, dim3(2048), dim3(256), 0, stream, idx, emb, xh);
  hipLaunchKernelGGL(gx_kernel, dim3(256, 16), dim3(256), 0, stream, xh, Wih0, bih0, bhh0, gx);
  hipLaunchKernelGGL(seq_kernel, dim3(32), dim3(512), 0, stream,
                     gx, Whh0, Wih1, Whh1, bih1, bhh1, h0b, h1b, cnt, out);
}

// Round 2
// 37932.932 us; speedup vs baseline: 1.0735x; 1.0735x over previous
//
#include <hip/hip_runtime.h>

typedef _Float16 f16;
typedef __attribute__((ext_vector_type(4))) _Float16 f16x4;
typedef __attribute__((ext_vector_type(8))) _Float16 f16x8;
typedef __attribute__((ext_vector_type(4))) float f32x4;

#define NB 8
#define NS 4096
#define NIN 512
#define NDIN 1024
#define NH 512
#define NG4 2048
#define NPROJ 960

// workspace layout (bytes)
static const size_t OFF_XH  = 0;                                  // f16 [NB*NS][NDIN]   = 64 MB
static const size_t OFF_GX  = (size_t)NB*NS*NDIN*2;               // f16 [NB*NS][NG4]    = 128 MB
static const size_t OFF_H0  = OFF_GX + (size_t)NB*NS*NG4*2;       // f16 [2][16][512]
static const size_t OFF_H1  = OFF_H0 + 32768;                     // f16 [2][16][512]
static const size_t OFF_ARR = OFF_H1 + 32768;                     // 32 arrival dwords + pad

__device__ __forceinline__ float sigf(float x)  { return 1.f/(1.f+__expf(-x)); }
__device__ __forceinline__ float tanh_(float x) { return 2.f/(1.f+__expf(-2.f*x)) - 1.f; }

__device__ __forceinline__ f16x8 cvt8(const float* p) {
  float4 a = *(const float4*)p;
  float4 b = *(const float4*)(p+4);
  f16x8 r = {(f16)a.x,(f16)a.y,(f16)a.z,(f16)a.w,(f16)b.x,(f16)b.y,(f16)b.z,(f16)b.w};
  return r;
}

// ---- LLC-coherent (cross-XCD) primitives: bypass L1/L2 with sc0 sc1 ----
__device__ __forceinline__ void st_h_coh(f16* p, float h) {
  f16 hf = (f16)h;
  unsigned short hv = *(unsigned short*)&hf;
  asm volatile("global_store_short %0, %1, off sc0 sc1" :: "v"(p), "v"(hv) : "memory");
}
__device__ __forceinline__ void st_flag(unsigned* p, unsigned v) {
  asm volatile("global_store_dword %0, %1, off sc0 sc1" :: "v"(p), "v"(v) : "memory");
}
__device__ __forceinline__ unsigned ld_flag(const unsigned* p) {
  unsigned v;
  asm volatile("global_load_dword %0, %1, off sc0 sc1\n\ts_waitcnt vmcnt(0)"
               : "=v"(v) : "v"(p) : "memory");
  return v;
}
__device__ __forceinline__ void drain_vm() {
  asm volatile("s_waitcnt vmcnt(0)" ::: "memory");
}

// relaxed-spin barrier: per-WG arrival flags, one acquire fence on exit
__device__ __forceinline__ void phase_barrier(unsigned* arr, int wg, unsigned tgt) {
  __syncthreads();                       // all waves of this WG drained their h stores
  if (threadIdx.x < 64) {
    if (threadIdx.x == 0) st_flag(arr + wg, tgt);
    const unsigned* ap = arr + (threadIdx.x & 31);
    unsigned v;
    do { v = ld_flag(ap); } while (!__all((int)(v >= tgt)));
    __builtin_amdgcn_fence(__ATOMIC_ACQUIRE, "agent");   // one L1/L2 inv per phase
  }
  __syncthreads();
}

__global__ void init_kernel(unsigned* __restrict__ p, int n) {
  int i = blockIdx.x*blockDim.x + threadIdx.x;
  for (; i < n; i += gridDim.x*blockDim.x) p[i] = 0u;
}

// xh[bt][960+j] = emb[idx[bt]][j]
__global__ void emb_kernel(const int* __restrict__ idx, const float* __restrict__ emb,
                           f16* __restrict__ xh) {
  int g  = blockIdx.x*blockDim.x + threadIdx.x;   // 32768*16 threads
  int bt = g >> 4;
  int j  = (g & 15) << 2;
  int id = idx[bt];
  float4 v = *(const float4*)(emb + id*64 + j);
  f16x4 h = {(f16)v.x,(f16)v.y,(f16)v.z,(f16)v.w};
  *(f16x4*)(xh + (size_t)bt*NDIN + NPROJ + j) = h;
}

// xh[:, 0:960] = relu(WS @ Wp^T + bp), f16 out.  M=32768, N=960(pad 1024), K=512
__global__ __launch_bounds__(256) void proj_kernel(
    const float* __restrict__ wst, const float* __restrict__ Wp,
    const float* __restrict__ bp, f16* __restrict__ xh) {
  __shared__ f16 Asl[128*40];
  __shared__ f16 Bsl[128*40];
  const int tid = threadIdx.x;
  const int lane = tid & 63;
  const int wv = tid >> 6;
  const int wm = wv >> 1, wn = wv & 1;
  const int lm = lane & 15;
  const int kq = lane >> 4;
  const int kg8 = kq << 3;
  const int m0 = blockIdx.x * 128;
  const int n0 = blockIdx.y * 128;
  f32x4 acc[4][4];
#pragma unroll
  for (int a = 0; a < 4; ++a)
#pragma unroll
    for (int b = 0; b < 4; ++b) acc[a][b] = (f32x4){0.f,0.f,0.f,0.f};
  for (int k0 = 0; k0 < NIN; k0 += 32) {
#pragma unroll
    for (int i = 0; i < 4; ++i) {
      int c = tid + (i << 8);
      int row = c >> 3;
      int kc = (c & 7) << 2;
      {
        float4 v = *(const float4*)(wst + (size_t)(m0+row)*NIN + k0 + kc);
        f16x4 h = {(f16)v.x,(f16)v.y,(f16)v.z,(f16)v.w};
        *(f16x4*)&Asl[row*40 + kc] = h;
      }
      {
        int nr = n0 + row; nr = nr < NPROJ ? nr : (NPROJ-1);
        float4 v = *(const float4*)(Wp + (size_t)nr*NIN + k0 + kc);
        f16x4 h = {(f16)v.x,(f16)v.y,(f16)v.z,(f16)v.w};
        *(f16x4*)&Bsl[row*40 + kc] = h;
      }
    }
    __syncthreads();
    f16x8 af[4], bf[4];
#pragma unroll
    for (int f = 0; f < 4; ++f) af[f] = *(f16x8*)&Asl[(wm*64 + f*16 + lm)*40 + kg8];
#pragma unroll
    for (int f = 0; f < 4; ++f) bf[f] = *(f16x8*)&Bsl[(wn*64 + f*16 + lm)*40 + kg8];
#pragma unroll
    for (int a = 0; a < 4; ++a)
#pragma unroll
      for (int b = 0; b < 4; ++b)
        acc[a][b] = __builtin_amdgcn_mfma_f32_16x16x32_f16(af[a], bf[b], acc[a][b], 0,0,0);
    __syncthreads();
  }
#pragma unroll
  for (int a = 0; a < 4; ++a)
#pragma unroll
    for (int b = 0; b < 4; ++b) {
      int n = n0 + wn*64 + b*16 + lm;
      if (n < NPROJ) {
        float bias = bp[n];
#pragma unroll
        for (int j = 0; j < 4; ++j) {
          int m = m0 + wm*64 + a*16 + (kq<<2) + j;
          float v = acc[a][b][j] + bias;
          xh[(size_t)m*NDIN + n] = (f16)fmaxf(v, 0.f);
        }
      }
    }
}

// gx = xh @ Wih0p^T + b0p (gate-permuted cols: prow=4u+g <- orig g*512+u). f16 out.
__global__ __launch_bounds__(256) void gx_kernel(
    const f16* __restrict__ xh, const float* __restrict__ Wih0,
    const float* __restrict__ bih0, const float* __restrict__ bhh0,
    f16* __restrict__ gx) {
  __shared__ f16 Asl[128*40];
  __shared__ f16 Bsl[128*40];
  const int tid = threadIdx.x;
  const int lane = tid & 63;
  const int wv = tid >> 6;
  const int wm = wv >> 1, wn = wv & 1;
  const int lm = lane & 15;
  const int kq = lane >> 4;
  const int kg8 = kq << 3;
  const int m0 = blockIdx.x * 128;
  const int n0 = blockIdx.y * 128;
  f32x4 acc[4][4];
#pragma unroll
  for (int a = 0; a < 4; ++a)
#pragma unroll
    for (int b = 0; b < 4; ++b) acc[a][b] = (f32x4){0.f,0.f,0.f,0.f};
  for (int k0 = 0; k0 < NDIN; k0 += 32) {
#pragma unroll
    for (int i = 0; i < 2; ++i) {                 // A: 512 chunks of 8 halves
      int c = tid + (i << 8);
      int row = c >> 2;
      int kc = (c & 3) << 3;
      f16x8 v = *(const f16x8*)(xh + (size_t)(m0+row)*NDIN + k0 + kc);
      *(f16x8*)&Asl[row*40 + kc] = v;
    }
#pragma unroll
    for (int i = 0; i < 4; ++i) {                 // B: permuted Wih0 rows, fp32->f16
      int c = tid + (i << 8);
      int row = c >> 3;
      int kc = (c & 7) << 2;
      int n = n0 + row;
      int orig = ((n & 3) << 9) | (n >> 2);
      float4 v = *(const float4*)(Wih0 + (size_t)orig*NDIN + k0 + kc);
      f16x4 h = {(f16)v.x,(f16)v.y,(f16)v.z,(f16)v.w};
      *(f16x4*)&Bsl[row*40 + kc] = h;
    }
    __syncthreads();
    f16x8 af[4], bf[4];
#pragma unroll
    for (int f = 0; f < 4; ++f) af[f] = *(f16x8*)&Asl[(wm*64 + f*16 + lm)*40 + kg8];
#pragma unroll
    for (int f = 0; f < 4; ++f) bf[f] = *(f16x8*)&Bsl[(wn*64 + f*16 + lm)*40 + kg8];
#pragma unroll
    for (int a = 0; a < 4; ++a)
#pragma unroll
      for (int b = 0; b < 4; ++b)
        acc[a][b] = __builtin_amdgcn_mfma_f32_16x16x32_f16(af[a], bf[b], acc[a][b], 0,0,0);
    __syncthreads();
  }
#pragma unroll
  for (int a = 0; a < 4; ++a)
#pragma unroll
    for (int b = 0; b < 4; ++b) {
      int n = n0 + wn*64 + b*16 + lm;
      int orig = ((n & 3) << 9) | (n >> 2);
      float bias = bih0[orig] + bhh0[orig];
#pragma unroll
      for (int j = 0; j < 4; ++j) {
        int m = m0 + wm*64 + a*16 + (kq<<2) + j;
        gx[(size_t)m*NG4 + n] = (f16)(acc[a][b][j] + bias);
      }
    }
}

// Persistent sequential LSTM. 32 WGs x 512 thr = 256 waves.
// blocks 0..15  (128 waves): layer-0 gate tiles, step k
// blocks 16..31 (128 waves): layer-1 gate tiles, step k-1
__global__ __launch_bounds__(512, 2) void seq_kernel(
    const f16* __restrict__ gx, const float* __restrict__ Whh0,
    const float* __restrict__ Wih1, const float* __restrict__ Whh1,
    const float* __restrict__ bih1, const float* __restrict__ bhh1,
    f16* __restrict__ h0b, f16* __restrict__ h1b,
    unsigned* __restrict__ arr, float* __restrict__ out) {
  const int tid  = threadIdx.x;
  const int lane = tid & 63;
  const int lm  = lane & 15;         // A-row-in-tile / D-col(batch)
  const int kq  = lane >> 4;         // k-quarter / D-row-group
  const int kg8 = kq << 3;
  const size_t HID = (size_t)NB*NS*NH;   // 16777216

  if (blockIdx.x < 16) {
    // ---------------- layer 0 ----------------
    const int rt = (blockIdx.x << 3) + (tid >> 6);      // 0..127
    const int prow = (rt << 4) + lm;
    const int orig = ((prow & 3) << 9) | (prow >> 2);
    const int u    = (rt << 2) + kq;
    const int bb   = (lm < 8) ? lm : 0;
    const bool act = (lm < 8);

    f16x8 wA[16];
    {
      const float* s = Whh0 + (size_t)orig * NH;
#pragma unroll
      for (int kt = 0; kt < 16; ++kt) wA[kt] = cvt8(s + kt*32 + kg8);
#pragma unroll
      for (int kt = 0; kt < 16; ++kt) asm volatile("" : "+v"(wA[kt]));
    }

    float cst = 0.f, hlast = 0.f;
    f16x4 gcur = *(const f16x4*)(gx + ((size_t)bb*NS)*NG4 + (u << 2));

    for (int k = 0; k < NS; ++k) {
      f16x4 gnxt = gcur;
      if (k + 1 < NS)
        gnxt = *(const f16x4*)(gx + ((size_t)bb*NS + (k+1))*NG4 + (u << 2));
      const f16* hp = h0b + ((k+1)&1)*8192 + (lm << 9);
      f32x4 a0 = (f32x4){0.f,0.f,0.f,0.f}, a1 = (f32x4){0.f,0.f,0.f,0.f};
#pragma unroll
      for (int kt = 0; kt < 16; kt += 2) {
        a0 = __builtin_amdgcn_mfma_f32_16x16x32_f16(wA[kt],   *(const f16x8*)(hp + kt*32 + kg8),      a0, 0,0,0);
        a1 = __builtin_amdgcn_mfma_f32_16x16x32_f16(wA[kt+1], *(const f16x8*)(hp + kt*32 + 32 + kg8), a1, 0,0,0);
      }
      float gi = a0[0] + a1[0] + (float)gcur[0];
      float gf = a0[1] + a1[1] + (float)gcur[1];
      float gg = a0[2] + a1[2] + (float)gcur[2];
      float go = a0[3] + a1[3] + (float)gcur[3];
      cst = sigf(gf)*cst + sigf(gi)*tanh_(gg);
      float h = sigf(go)*tanh_(cst);
      hlast = h;
      if (act) st_h_coh(h0b + (k&1)*8192 + (lm << 9) + u, h);
      drain_vm();
      gcur = gnxt;
      phase_barrier(arr, blockIdx.x, (unsigned)(k+1));
    }
    if (act) {
      size_t base = (size_t)lm*NH + u;
      out[HID + base] = hlast;               // hidden[0]
      out[HID + 8192 + base] = cst;          // cell[0]
    }
  } else {
    // ---------------- layer 1 ----------------
    const int rt = ((blockIdx.x - 16) << 3) + (tid >> 6);   // 0..127
    const int prow = (rt << 4) + lm;
    const int orig = ((prow & 3) << 9) | (prow >> 2);
    const int u    = (rt << 2) + kq;
    const bool act = (lm < 8);

    f16x8 wA[16], wB[16];
    {
      const float* s1 = Wih1 + (size_t)orig * NH;
      const float* s2 = Whh1 + (size_t)orig * NH;
#pragma unroll
      for (int kt = 0; kt < 16; ++kt) wA[kt] = cvt8(s1 + kt*32 + kg8);
#pragma unroll
      for (int kt = 0; kt < 16; ++kt) wB[kt] = cvt8(s2 + kt*32 + kg8);
#pragma unroll
      for (int kt = 0; kt < 16; ++kt) {
        asm volatile("" : "+v"(wA[kt]));
        asm volatile("" : "+v"(wB[kt]));
      }
    }
    float bias1_[4];
#pragma unroll
    for (int j = 0; j < 4; ++j) bias1_[j] = bih1[j*NH + u] + bhh1[j*NH + u];

    float cst = 0.f, hlast = 0.f;

    auto g1_step = [&](int k, bool final_) {
      const f16* hp0 = h0b + ((k+1)&1)*8192 + (lm << 9);   // h0(k-1)
      const f16* hp1 = h1b + (k&1)*8192 + (lm << 9);       // h1(k-2)
      f32x4 a0 = (f32x4){0.f,0.f,0.f,0.f}, a1 = (f32x4){0.f,0.f,0.f,0.f};
#pragma unroll
      for (int kt = 0; kt < 16; ++kt)
        a0 = __builtin_amdgcn_mfma_f32_16x16x32_f16(wA[kt], *(const f16x8*)(hp0 + kt*32 + kg8), a0, 0,0,0);
#pragma unroll
      for (int kt = 0; kt < 16; ++kt)
        a1 = __builtin_amdgcn_mfma_f32_16x16x32_f16(wB[kt], *(const f16x8*)(hp1 + kt*32 + kg8), a1, 0,0,0);
      float gi = a0[0] + a1[0] + bias1_[0];
      float gf = a0[1] + a1[1] + bias1_[1];
      float gg = a0[2] + a1[2] + bias1_[2];
      float go = a0[3] + a1[3] + bias1_[3];
      cst = sigf(gf)*cst + sigf(gi)*tanh_(gg);
      float h = sigf(go)*tanh_(cst);
      hlast = h;
      if (act) {
        if (!final_) st_h_coh(h1b + ((k+1)&1)*8192 + (lm << 9) + u, h);
        out[((size_t)lm*NS + (k-1))*NH + u] = h;           // rnn_out fp32
      }
    };

    for (int k = 0; k < NS; ++k) {
      if (k >= 1) g1_step(k, false);
      drain_vm();
      phase_barrier(arr, blockIdx.x, (unsigned)(k+1));
    }
    g1_step(NS, true);                                     // step NS-1, no publish

    if (act) {
      size_t base = (size_t)lm*NH + u;
      out[HID + 4096 + base] = hlast;        // hidden[1]
      out[HID + 8192 + 4096 + base] = cst;   // cell[1]
    }
  }
}

extern "C" void kernel_launch(void* const* d_in, const int* in_sizes, int n_in,
                              void* d_out, int out_size, void* d_ws, size_t ws_size,
                              hipStream_t stream) {
  const float* wst  = (const float*)d_in[0];
  const int*   idx  = (const int*)  d_in[1];
  const float* emb  = (const float*)d_in[2];
  const float* Wp   = (const float*)d_in[3];
  const float* bp   = (const float*)d_in[4];
  const float* Wih0 = (const float*)d_in[5];
  const float* Whh0 = (const float*)d_in[6];
  const float* bih0 = (const float*)d_in[7];
  const float* bhh0 = (const float*)d_in[8];
  const float* Wih1 = (const float*)d_in[9];
  const float* Whh1 = (const float*)d_in[10];
  const float* bih1 = (const float*)d_in[11];
  const float* bhh1 = (const float*)d_in[12];
  float* out = (float*)d_out;
  char* wsb = (char*)d_ws;
  f16* xh  = (f16*)(wsb + OFF_XH);
  f16* gx  = (f16*)(wsb + OFF_GX);
  f16* h0b = (f16*)(wsb + OFF_H0);
  f16* h1b = (f16*)(wsb + OFF_H1);
  unsigned* arr = (unsigned*)(wsb + OFF_ARR);

  // zero h buffers + arrival flags (ws is poisoned before every launch)
  hipLaunchKernelGGL(init_kernel, dim3(32), dim3(256), 0, stream,
                     (unsigned*)(wsb + OFF_H0), (int)((32768 + 32768 + 256) / 4));
  hipLaunchKernelGGL(proj_kernel, dim3(256, 8), dim3(256), 0, stream, wst, Wp, bp, xh);
  hipLaunchKernelGGL(emb_kernel, dim3(2048), dim3(256), 0, stream, idx, emb, xh);
  hipLaunchKernelGGL(gx_kernel, dim3(256, 16), dim3(256), 0, stream, xh, Wih0, bih0, bhh0, gx);
  hipLaunchKernelGGL(seq_kernel, dim3(32), dim3(512), 0, stream,
                     gx, Whh0, Wih1, Whh1, bih1, bhh1, h0b, h1b, arr, out);
}